// Round 4
// baseline (1128.715 us; speedup 1.0000x reference)
//
#include <hip/hip_runtime.h>

#define MM 1024
#define NN 4096
#define DD 128
#define HH 32
#define PP 3072
#define LL 4096   // P + M

typedef __attribute__((ext_vector_type(8))) short short8;
typedef __attribute__((ext_vector_type(4))) float f32x4;

__device__ __forceinline__ float bf2f(short b) {
  union { unsigned u; float f; } c;
  c.u = ((unsigned)(unsigned short)b) << 16;
  return c.f;
}

__device__ __forceinline__ short f2bf(float f) {
  union { float f; unsigned u; } c; c.f = f;
  unsigned r = c.u + 0x7FFFu + ((c.u >> 16) & 1u);  // RNE
  return (short)(r >> 16);
}

// split f32 -> bf16 hi + bf16 lo (x ~= hi + lo, residual ~2^-16 rel)
struct bf2 { short hi, lo; };
__device__ __forceinline__ bf2 split2(float x) {
  bf2 r;
  r.hi = f2bf(x);
  r.lo = f2bf(x - bf2f(r.hi));
  return r;
}

// 8 consecutive f32 -> 8 bf16 (plain cast)
__device__ __forceinline__ short8 cvt8(const float* __restrict__ p) {
  const f32x4 a = *(const f32x4*)p;
  const f32x4 b = *(const f32x4*)(p + 4);
  short8 r;
  r[0] = f2bf(a[0]); r[1] = f2bf(a[1]); r[2] = f2bf(a[2]); r[3] = f2bf(a[3]);
  r[4] = f2bf(b[0]); r[5] = f2bf(b[1]); r[6] = f2bf(b[2]); r[7] = f2bf(b[3]);
  return r;
}

// ---------------------------------------------------------------------------
// Split X f32 -> Xhi, Xlo bf16 (8 elems/thread).
// ---------------------------------------------------------------------------
__global__ __launch_bounds__(256) void split_x(
    const float* __restrict__ in, short* __restrict__ oh,
    short* __restrict__ ol, int n8)
{
  int i = blockIdx.x * blockDim.x + threadIdx.x;
  if (i >= n8) return;
  const float* p = in + (size_t)i * 8;
  f32x4 a = *(const f32x4*)p, b = *(const f32x4*)(p + 4);
  short8 h, l;
  #pragma unroll
  for (int j = 0; j < 4; ++j) {
    bf2 ra = split2(a[j]); h[j] = ra.hi; l[j] = ra.lo;
    bf2 rb = split2(b[j]); h[4 + j] = rb.hi; l[4 + j] = rb.lo;
  }
  *(short8*)(oh + (size_t)i * 8) = h;
  *(short8*)(ol + (size_t)i * 8) = l;
}

// ---------------------------------------------------------------------------
// Split-precision GEMM for Q,K: O f32 [M][4096] = X @ W, 3-term bf16 split.
// Tile 128x128, BK=64, 4 waves (2x2 of 64x64), mfma 16x16x32.
// A (Xhi/Xlo) LDS stride 72; B (W split on the fly) LDS stride 136 with
// XOR column-block swizzle (cb ^= k>>3) so the 8x u16 B-frag gather puts the
// 4 quads in 4 distinct 16B blocks (no 8-way bank conflict).
// ---------------------------------------------------------------------------
__global__ __launch_bounds__(256) void gemm_qk_split(
    const short* __restrict__ Xhi, const short* __restrict__ Xlo,
    const float* __restrict__ Wq, const float* __restrict__ Wk,
    float* __restrict__ Oq, float* __restrict__ Ok)
{
  const int z = blockIdx.z;
  const float* __restrict__ W = (z == 0) ? Wq : Wk;
  float* __restrict__ O = (z == 0) ? Oq : Ok;

  const int n0 = blockIdx.x * 128;
  const int m0 = blockIdx.y * 128;
  const int t  = threadIdx.x;
  const int wave = t >> 6;
  const int lane = t & 63;
  const int ln   = lane & 15;
  const int quad = lane >> 4;
  const int q8   = quad * 8;
  const int wm = (wave >> 1) * 64;
  const int wn = (wave & 1) * 64;

  __shared__ short Ah[128 * 72];
  __shared__ short Al[128 * 72];
  __shared__ short Bh[64 * 136];
  __shared__ short Bl[64 * 136];

  f32x4 acc[4][4];
  #pragma unroll
  for (int mi = 0; mi < 4; ++mi)
    #pragma unroll
    for (int ni = 0; ni < 4; ++ni)
      acc[mi][ni] = (f32x4){0.f, 0.f, 0.f, 0.f};

  const int ar = t >> 3, ac = (t & 7) * 8;   // A: 32 rows/pass x 64 k
  const int bk = t >> 4, bn = (t & 15) * 8;  // B: 16 k-rows/pass x 128 n

  for (int kt = 0; kt < 4096; kt += 64) {
    #pragma unroll
    for (int i = 0; i < 4; ++i) {
      int r = i * 32 + ar;
      size_t off = (size_t)(m0 + r) * 4096 + kt + ac;
      *(short8*)(Ah + r * 72 + ac) = *(const short8*)(Xhi + off);
      *(short8*)(Al + r * 72 + ac) = *(const short8*)(Xlo + off);
    }
    #pragma unroll
    for (int i = 0; i < 4; ++i) {
      int kr = i * 16 + bk;
      const float* wp = W + (size_t)(kt + kr) * 4096 + n0 + bn;
      f32x4 x0 = *(const f32x4*)wp, x1 = *(const f32x4*)(wp + 4);
      short8 hh, ll;
      #pragma unroll
      for (int j = 0; j < 4; ++j) {
        bf2 r0 = split2(x0[j]); hh[j] = r0.hi; ll[j] = r0.lo;
        bf2 r1 = split2(x1[j]); hh[4 + j] = r1.hi; ll[4 + j] = r1.lo;
      }
      int cb = (bn >> 3) ^ (kr >> 3);
      *(short8*)(Bh + kr * 136 + cb * 8) = hh;
      *(short8*)(Bl + kr * 136 + cb * 8) = ll;
    }
    __syncthreads();
    #pragma unroll
    for (int kk = 0; kk < 64; kk += 32) {
      short8 afh[4], afl[4];
      #pragma unroll
      for (int mi = 0; mi < 4; ++mi) {
        int ro = (wm + mi * 16 + ln) * 72 + kk + q8;
        afh[mi] = *(const short8*)(Ah + ro);
        afl[mi] = *(const short8*)(Al + ro);
      }
      #pragma unroll
      for (int ni = 0; ni < 4; ++ni) {
        short8 bh, bl;
        #pragma unroll
        for (int j = 0; j < 8; ++j) {
          int k = kk + q8 + j;
          int idx = k * 136 + ((((wn + ni * 16 + ln) >> 3) ^ (k >> 3)) << 3) + (ln & 7);
          bh[j] = Bh[idx];
          bl[j] = Bl[idx];
        }
        #pragma unroll
        for (int mi = 0; mi < 4; ++mi) {
          acc[mi][ni] = __builtin_amdgcn_mfma_f32_16x16x32_bf16(afh[mi], bh, acc[mi][ni], 0, 0, 0);
          acc[mi][ni] = __builtin_amdgcn_mfma_f32_16x16x32_bf16(afh[mi], bl, acc[mi][ni], 0, 0, 0);
          acc[mi][ni] = __builtin_amdgcn_mfma_f32_16x16x32_bf16(afl[mi], bh, acc[mi][ni], 0, 0, 0);
        }
      }
    }
    __syncthreads();
  }

  #pragma unroll
  for (int mi = 0; mi < 4; ++mi)
    #pragma unroll
    for (int ni = 0; ni < 4; ++ni)
      #pragma unroll
      for (int r = 0; r < 4; ++r) {
        int row = m0 + wm + mi * 16 + quad * 4 + r;
        int col = n0 + wn + ni * 16 + ln;
        O[(size_t)row * 4096 + col] = acc[mi][ni][r];
      }
}

// ---------------------------------------------------------------------------
// Plain bf16 GEMM for V: O bf16 = Xhi @ Wv (cast on the fly). Same structure.
// ---------------------------------------------------------------------------
__global__ __launch_bounds__(256) void gemm_v(
    const short* __restrict__ Xhi, const float* __restrict__ Wv,
    short* __restrict__ Ov)
{
  const int n0 = blockIdx.x * 128;
  const int m0 = blockIdx.y * 128;
  const int t  = threadIdx.x;
  const int wave = t >> 6;
  const int lane = t & 63;
  const int ln   = lane & 15;
  const int quad = lane >> 4;
  const int q8   = quad * 8;
  const int wm = (wave >> 1) * 64;
  const int wn = (wave & 1) * 64;

  __shared__ short Ah[128 * 72];
  __shared__ short Bh[64 * 136];

  f32x4 acc[4][4];
  #pragma unroll
  for (int mi = 0; mi < 4; ++mi)
    #pragma unroll
    for (int ni = 0; ni < 4; ++ni)
      acc[mi][ni] = (f32x4){0.f, 0.f, 0.f, 0.f};

  const int ar = t >> 3, ac = (t & 7) * 8;
  const int bk = t >> 4, bn = (t & 15) * 8;

  for (int kt = 0; kt < 4096; kt += 64) {
    #pragma unroll
    for (int i = 0; i < 4; ++i) {
      int r = i * 32 + ar;
      *(short8*)(Ah + r * 72 + ac) =
          *(const short8*)(Xhi + (size_t)(m0 + r) * 4096 + kt + ac);
    }
    #pragma unroll
    for (int i = 0; i < 4; ++i) {
      int kr = i * 16 + bk;
      int cb = (bn >> 3) ^ (kr >> 3);
      *(short8*)(Bh + kr * 136 + cb * 8) =
          cvt8(Wv + (size_t)(kt + kr) * 4096 + n0 + bn);
    }
    __syncthreads();
    #pragma unroll
    for (int kk = 0; kk < 64; kk += 32) {
      short8 afh[4];
      #pragma unroll
      for (int mi = 0; mi < 4; ++mi)
        afh[mi] = *(const short8*)(Ah + (wm + mi * 16 + ln) * 72 + kk + q8);
      #pragma unroll
      for (int ni = 0; ni < 4; ++ni) {
        short8 bh;
        #pragma unroll
        for (int j = 0; j < 8; ++j) {
          int k = kk + q8 + j;
          int idx = k * 136 + ((((wn + ni * 16 + ln) >> 3) ^ (k >> 3)) << 3) + (ln & 7);
          bh[j] = Bh[idx];
        }
        #pragma unroll
        for (int mi = 0; mi < 4; ++mi)
          acc[mi][ni] = __builtin_amdgcn_mfma_f32_16x16x32_bf16(afh[mi], bh, acc[mi][ni], 0, 0, 0);
      }
    }
    __syncthreads();
  }

  #pragma unroll
  for (int mi = 0; mi < 4; ++mi)
    #pragma unroll
    for (int ni = 0; ni < 4; ++ni)
      #pragma unroll
      for (int r = 0; r < 4; ++r) {
        int row = m0 + wm + mi * 16 + quad * 4 + r;
        int col = n0 + wn + ni * 16 + ln;
        Ov[(size_t)row * 4096 + col] = f2bf(acc[mi][ni][r]);
      }
}

// ---------------------------------------------------------------------------
// RMS-norm f32 in place per (row, head): 8 lanes/head, 16 f32/lane.
// grid (1024, 2): y==0 -> Q, y==1 -> K.
// ---------------------------------------------------------------------------
__global__ __launch_bounds__(256) void rmsnorm_f32(
    float* __restrict__ Q, float* __restrict__ K)
{
  float* __restrict__ buf = (blockIdx.y == 0) ? Q : K;
  const int m = blockIdx.x;
  const int t = threadIdx.x;
  const int head = t >> 3, li = t & 7;
  size_t base = (size_t)m * 4096 + head * 128 + li * 16;

  f32x4 a[4];
  float ss = 0.f;
  #pragma unroll
  for (int i = 0; i < 4; ++i) {
    a[i] = *(const f32x4*)(buf + base + i * 4);
    #pragma unroll
    for (int j = 0; j < 4; ++j) ss += a[i][j] * a[i][j];
  }
  #pragma unroll
  for (int d = 1; d < 8; d <<= 1) ss += __shfl_xor(ss, d, 64);
  float scale = rsqrtf(ss * (1.0f / 128.0f));
  #pragma unroll
  for (int i = 0; i < 4; ++i) {
    #pragma unroll
    for (int j = 0; j < 4; ++j) a[i][j] *= scale;
    *(f32x4*)(buf + base + i * 4) = a[i];
  }
}

// ---------------------------------------------------------------------------
// Flash attention, 64 q-rows/block, 4 waves (wave w owns q-rows 16w..16w+16
// for QK^T + softmax; owns d-subtiles {2w,2w+1} for PV).
// QK^T in 3-term bf16 split (q,k split on the fly from f32 sources).
// In-register wave-private online softmax. P round-trips LDS as bf16.
// V natural [key][d] LDS with XOR block swizzle for the u16 frag gather.
// ---------------------------------------------------------------------------
__global__ __launch_bounds__(256) void attn(
    const float* __restrict__ Qf,   // [M][4096] f32 rms-normed q
    const float* __restrict__ Kf,   // [M][4096] f32 rms-normed k
    const short* __restrict__ Vb,   // [M][4096] bf16 v
    const float* __restrict__ cK,   // [H][P][D] f32
    const float* __restrict__ cV,   // [H][P][D] f32
    float* __restrict__ Out)        // [M][4096] f32
{
  const int h  = blockIdx.y;
  const int m0 = blockIdx.x * 64;
  const int t  = threadIdx.x;
  const int w    = t >> 6;
  const int lane = t & 63;
  const int ln   = lane & 15;
  const int quad = lane >> 4;
  const int q8   = quad * 8;

  __shared__ short k_hi[64 * 136];
  __shared__ short k_lo[64 * 136];
  __shared__ short v_s[64 * 136];
  __shared__ short p_s[64 * 72];
  __shared__ float a_l[64], l_l[64];

  // q fragments from global, split in registers (A layout: m=ln, k=q8+j)
  short8 qh[4], ql[4];
  {
    int qrow = m0 + w * 16 + ln;
    #pragma unroll
    for (int dc = 0; dc < 4; ++dc) {
      const float* qp = Qf + (size_t)qrow * 4096 + h * 128 + dc * 32 + q8;
      f32x4 a = *(const f32x4*)qp, b = *(const f32x4*)(qp + 4);
      #pragma unroll
      for (int j = 0; j < 4; ++j) {
        bf2 ra = split2(a[j]); qh[dc][j] = ra.hi; ql[dc][j] = ra.lo;
        bf2 rb = split2(b[j]); qh[dc][4 + j] = rb.hi; ql[dc][4 + j] = rb.lo;
      }
    }
  }

  float m_st[4], l_st[4];
  #pragma unroll
  for (int r = 0; r < 4; ++r) { m_st[r] = -1e30f; l_st[r] = 0.f; }

  f32x4 oacc[4][2];
  #pragma unroll
  for (int ms = 0; ms < 4; ++ms)
    #pragma unroll
    for (int i = 0; i < 2; ++i)
      oacc[ms][i] = (f32x4){0.f, 0.f, 0.f, 0.f};

  for (int kb = 0; kb < LL; kb += 64) {
    // ---- stage K (split) and V (bf16) : 64 keys x 128 d
    #pragma unroll
    for (int i = 0; i < 2; ++i) {
      int kr = i * 32 + (t >> 3);
      int g  = kb + kr;
      int dc = (t & 7) * 16;
      const float* ks = (g < PP)
          ? cK + ((size_t)h * PP + g) * 128 + dc
          : Kf + (size_t)(g - PP) * 4096 + h * 128 + dc;
      f32x4 x0 = *(const f32x4*)ks,       x1 = *(const f32x4*)(ks + 4);
      f32x4 x2 = *(const f32x4*)(ks + 8), x3 = *(const f32x4*)(ks + 12);
      short8 h0, l0, h1, l1;
      #pragma unroll
      for (int j = 0; j < 4; ++j) {
        bf2 r0 = split2(x0[j]); h0[j] = r0.hi; l0[j] = r0.lo;
        bf2 r1 = split2(x1[j]); h0[4 + j] = r1.hi; l0[4 + j] = r1.lo;
        bf2 r2 = split2(x2[j]); h1[j] = r2.hi; l1[j] = r2.lo;
        bf2 r3 = split2(x3[j]); h1[4 + j] = r3.hi; l1[4 + j] = r3.lo;
      }
      *(short8*)(k_hi + kr * 136 + dc)     = h0;
      *(short8*)(k_hi + kr * 136 + dc + 8) = h1;
      *(short8*)(k_lo + kr * 136 + dc)     = l0;
      *(short8*)(k_lo + kr * 136 + dc + 8) = l1;

      short8 v0, v1;
      if (g < PP) {
        const float* vs = cV + ((size_t)h * PP + g) * 128 + dc;
        v0 = cvt8(vs); v1 = cvt8(vs + 8);
      } else {
        const short* vp = Vb + (size_t)(g - PP) * 4096 + h * 128 + dc;
        v0 = *(const short8*)vp; v1 = *(const short8*)(vp + 8);
      }
      int b0 = ((dc >> 3) + 0) ^ (kr >> 3);
      int b1 = ((dc >> 3) + 1) ^ (kr >> 3);
      *(short8*)(v_s + kr * 136 + b0 * 8) = v0;
      *(short8*)(v_s + kr * 136 + b1 * 8) = v1;
    }
    __syncthreads();

    // ---- S = q K^T (wave's 16 rows x 64 keys), 3-term split
    f32x4 sacc[4];
    #pragma unroll
    for (int ni = 0; ni < 4; ++ni) sacc[ni] = (f32x4){0.f, 0.f, 0.f, 0.f};
    #pragma unroll
    for (int ni = 0; ni < 4; ++ni) {
      #pragma unroll
      for (int dc = 0; dc < 4; ++dc) {
        int ro = (ni * 16 + ln) * 136 + dc * 32 + q8;
        short8 kh = *(const short8*)(k_hi + ro);
        short8 kl = *(const short8*)(k_lo + ro);
        sacc[ni] = __builtin_amdgcn_mfma_f32_16x16x32_bf16(qh[dc], kh, sacc[ni], 0, 0, 0);
        sacc[ni] = __builtin_amdgcn_mfma_f32_16x16x32_bf16(qh[dc], kl, sacc[ni], 0, 0, 0);
        sacc[ni] = __builtin_amdgcn_mfma_f32_16x16x32_bf16(ql[dc], kh, sacc[ni], 0, 0, 0);
      }
    }

    // ---- wave-private online softmax (rows quad*4+rr of this wave)
    float alpha[4];
    #pragma unroll
    for (int rr = 0; rr < 4; ++rr) {
      float mx = fmaxf(fmaxf(sacc[0][rr], sacc[1][rr]),
                       fmaxf(sacc[2][rr], sacc[3][rr]));
      #pragma unroll
      for (int d = 1; d < 16; d <<= 1) mx = fmaxf(mx, __shfl_xor(mx, d, 64));
      float mn = fmaxf(m_st[rr], mx);
      alpha[rr] = __expf(m_st[rr] - mn);
      float p0 = __expf(sacc[0][rr] - mn);
      float p1 = __expf(sacc[1][rr] - mn);
      float p2 = __expf(sacc[2][rr] - mn);
      float p3 = __expf(sacc[3][rr] - mn);
      float s = p0 + p1 + p2 + p3;
      #pragma unroll
      for (int d = 1; d < 16; d <<= 1) s += __shfl_xor(s, d, 64);
      l_st[rr] = l_st[rr] * alpha[rr] + s;
      m_st[rr] = mn;
      int prow = (w * 16 + quad * 4 + rr) * 72;
      p_s[prow + 0 * 16 + ln] = f2bf(p0);
      p_s[prow + 1 * 16 + ln] = f2bf(p1);
      p_s[prow + 2 * 16 + ln] = f2bf(p2);
      p_s[prow + 3 * 16 + ln] = f2bf(p3);
    }
    if (ln == 0) {
      #pragma unroll
      for (int rr = 0; rr < 4; ++rr) a_l[w * 16 + quad * 4 + rr] = alpha[rr];
    }
    __syncthreads();

    // ---- rescale O, then O += P V (wave owns d-subtiles 2w, 2w+1)
    #pragma unroll
    for (int ms = 0; ms < 4; ++ms) {
      f32x4 av = *(const f32x4*)(a_l + ms * 16 + quad * 4);
      #pragma unroll
      for (int i = 0; i < 2; ++i)
        #pragma unroll
        for (int r = 0; r < 4; ++r) oacc[ms][i][r] *= av[r];
    }
    #pragma unroll
    for (int kk = 0; kk < 64; kk += 32) {
      short8 vf[2];
      #pragma unroll
      for (int i = 0; i < 2; ++i) {
        int cbb = (w * 2 + i) * 2 + (ln >> 3);
        #pragma unroll
        for (int j = 0; j < 8; ++j) {
          int k = kk + q8 + j;
          vf[i][j] = v_s[k * 136 + ((cbb ^ (k >> 3)) << 3) + (ln & 7)];
        }
      }
      #pragma unroll
      for (int ms = 0; ms < 4; ++ms) {
        short8 pf = *(const short8*)(p_s + (ms * 16 + ln) * 72 + kk + q8);
        #pragma unroll
        for (int i = 0; i < 2; ++i)
          oacc[ms][i] = __builtin_amdgcn_mfma_f32_16x16x32_bf16(pf, vf[i], oacc[ms][i], 0, 0, 0);
      }
    }
    __syncthreads();
  }

  if (ln == 0) {
    #pragma unroll
    for (int rr = 0; rr < 4; ++rr) l_l[w * 16 + quad * 4 + rr] = l_st[rr];
  }
  __syncthreads();

  #pragma unroll
  for (int ms = 0; ms < 4; ++ms) {
    f32x4 lv = *(const f32x4*)(l_l + ms * 16 + quad * 4);
    #pragma unroll
    for (int i = 0; i < 2; ++i) {
      int col = h * 128 + (w * 2 + i) * 16 + ln;
      #pragma unroll
      for (int r = 0; r < 4; ++r) {
        int row = m0 + ms * 16 + quad * 4 + r;
        Out[(size_t)row * 4096 + col] = oacc[ms][i][r] / lv[r];
      }
    }
  }
}

// ---------------------------------------------------------------------------
extern "C" void kernel_launch(void* const* d_in, const int* in_sizes, int n_in,
                              void* d_out, int out_size, void* d_ws, size_t ws_size,
                              hipStream_t stream) {
  const float* X  = (const float*)d_in[0];
  const float* Wq = (const float*)d_in[1];
  const float* Wk = (const float*)d_in[2];
  const float* Wv = (const float*)d_in[3];
  const float* cK = (const float*)d_in[4];
  const float* cV = (const float*)d_in[5];
  float* out = (float*)d_out;

  const size_t E = (size_t)MM * NN;          // 4,194,304 elements
  short* Xh = (short*)d_ws;                  // bf16 [M][N]  8 MB
  short* Xl = Xh + E;                        // bf16 [M][N]  8 MB
  short* Vb = Xl + E;                        // bf16 [M][N]  8 MB
  float* Qf = (float*)(Vb + E);              // f32  [M][N] 16 MB
  float* Kf = Qf + E;                        // f32  [M][N] 16 MB

  {
    int n8 = (int)(E / 8);
    split_x<<<n8 / 256, 256, 0, stream>>>(X, Xh, Xl, n8);
  }

  dim3 gqk(NN / 128, MM / 128, 2);
  gemm_qk_split<<<gqk, 256, 0, stream>>>(Xh, Xl, Wq, Wk, Qf, Kf);

  dim3 gv(NN / 128, MM / 128);
  gemm_v<<<gv, 256, 0, stream>>>(Xh, Wv, Vb);

  dim3 gn(MM, 2);
  rmsnorm_f32<<<gn, 256, 0, stream>>>(Qf, Kf);

  dim3 ga(MM / 64, HH);
  attn<<<ga, 256, 0, stream>>>(Qf, Kf, Vb, cK, cV, out);
}